// Round 6
// baseline (178.427 us; speedup 1.0000x reference)
//
#include <hip/hip_runtime.h>
#include <hip/hip_bf16.h>

namespace {

constexpr int Bc = 4, Hc = 16, Sc = 2048, Dc = 64;

using bf16x2 = __attribute__((ext_vector_type(2))) __bf16;
using bf16x8 = __attribute__((ext_vector_type(8))) __bf16;
using f32x4  = __attribute__((ext_vector_type(4))) float;
using f32x16 = __attribute__((ext_vector_type(16))) float;
using uint4v = __attribute__((ext_vector_type(4))) unsigned int;

__device__ __forceinline__ float exp2_hw(float x) {
#if __has_builtin(__builtin_amdgcn_exp2f)
  return __builtin_amdgcn_exp2f(x);
#else
  return exp2f(x);
#endif
}

__device__ __forceinline__ unsigned pk_bf16(float a, float b) {
  bf16x2 t = { (__bf16)a, (__bf16)b };
  return __builtin_bit_cast(unsigned, t);
}

// v_permlane32_swap_b32 a,b with s_nop hazard padding (raw asm bypasses the
// post-RA hazard recognizer). Operands must be DISTINCT live values.
__device__ __forceinline__ void pl32swap(unsigned& a, unsigned& b) {
  asm volatile("s_nop 1\n\tv_permlane32_swap_b32 %0, %1\n\ts_nop 1"
               : "+v"(a), "+v"(b));
}
// Early-clobber dual-mov guarantees the two swap operands sit in distinct regs
// (round-3 lesson: copies of one SSA value may share a VGPR).
__device__ __forceinline__ void xhalf_pair(float x, float& lo, float& hi) {
  unsigned a, b;
  asm volatile("v_mov_b32 %0, %2\n\t"
               "v_mov_b32 %1, %2\n\t"
               "s_nop 1\n\t"
               "v_permlane32_swap_b32 %0, %1\n\t"
               "s_nop 1"
               : "=&v"(a), "=&v"(b)
               : "v"(x));
  lo = __builtin_bit_cast(float, a);
  hi = __builtin_bit_cast(float, b);
}
__device__ __forceinline__ float xhalf_max(float x) {
  float lo, hi; xhalf_pair(x, lo, hi); return fmaxf(lo, hi);
}
__device__ __forceinline__ float xhalf_sum(float x) {
  float lo, hi; xhalf_pair(x, lo, hi); return lo + hi;
}

__device__ __forceinline__ int vswz(int d) { return ((d >> 4) ^ d) & 7; }

// Block = 4 waves x 32 q-rows = ONE 128-row q-panel (tiles = 2p+2).
// Grid = 1024 blocks, 4 blocks/CU co-resident (launch_bounds(256,4)).
// Dispatch-order LPT: XCD = d&7 (hardware round-robin), within each XCD
// panels issue longest-first, so dynamic scheduling keeps CUs full; the
// short panels drain into the tail. bh stays clustered per XCD (L2 reuse).
__global__ __launch_bounds__(256, 4)
void fattn_kernel(const float* __restrict__ Q, const float* __restrict__ K,
                  const float* __restrict__ V, float* __restrict__ O) {
  const int tid  = threadIdx.x;
  const int wid  = tid >> 6;
  const int lane = tid & 63;
  const int l31  = lane & 31;
  const int hi   = lane >> 5;

  // d -> (xcd, bh, panel): bijective; per-XCD order = descending panel length.
  const int d    = blockIdx.x;
  const int x    = d & 7;
  const int q8   = (d >> 3) & 7;
  const int p    = 15 - (d >> 6);
  const int bh   = x * 8 + q8;

  const int qb = p * 128;
  const int wq = qb + wid * 32;
  const int nkb = 2 * p + 2;

  const size_t base = (size_t)bh * (Sc * Dc);
  const float* Qb = Q + base;
  const float* Kb = K + base;
  const float* Vb = V + base;
  float*       Ob = O + base;

  __shared__ __align__(16) __bf16 k_lds[2][64][64];   // K[k][d],  col ^= (k&7)<<3
  __shared__ __align__(16) __bf16 vt_lds[2][64][64];  // V^T[d][k], k ^= vswz(d)<<3

  const int srow = tid >> 2;         // staging row 0..63
  const int scol = (tid & 3) * 16;   // staging col chunk
  const int ssw  = (srow & 7) << 3;

  constexpr float QSC = 0.125f * 1.44269504088896f;  // 1/sqrt(D) * log2(e)

  // ---- Q fragment: lane holds Q[wq + l31][d = s*16 + hi*8 + j] ----
  bf16x8 qf[4];
  {
    const float* qrow = Qb + (size_t)(wq + l31) * Dc;
    #pragma unroll
    for (int s = 0; s < 4; ++s) {
      const float* src = qrow + s * 16 + hi * 8;
      f32x4 a0 = *(const f32x4*)src;
      f32x4 a1 = *(const f32x4*)(src + 4);
      uint4v wv;
      wv[0] = pk_bf16(a0[0] * QSC, a0[1] * QSC);
      wv[1] = pk_bf16(a0[2] * QSC, a0[3] * QSC);
      wv[2] = pk_bf16(a1[0] * QSC, a1[1] * QSC);
      wv[3] = pk_bf16(a1[2] * QSC, a1[3] * QSC);
      qf[s] = __builtin_bit_cast(bf16x8, wv);
    }
  }

  f32x16 o0, o1;   // O^T: col q = l31; row d = dh*32 + (i&3) + 8*(i>>2) + 4*hi
  #pragma unroll
  for (int i = 0; i < 16; ++i) { o0[i] = 0.f; o1[i] = 0.f; }
  float m = -1e30f, l = 0.f;

  // ---- prologue: stage tile 0 into buffer 0 ----
  {
    const float* ksrc = Kb + (size_t)srow * Dc + scol;
    f32x4 a0 = *(const f32x4*)ksrc;
    f32x4 a1 = *(const f32x4*)(ksrc + 4);
    f32x4 a2 = *(const f32x4*)(ksrc + 8);
    f32x4 a3 = *(const f32x4*)(ksrc + 12);
    const float* vsrc = Vb + (size_t)srow * Dc + scol;
    f32x4 b0 = *(const f32x4*)vsrc;
    f32x4 b1 = *(const f32x4*)(vsrc + 4);
    f32x4 b2 = *(const f32x4*)(vsrc + 8);
    f32x4 b3 = *(const f32x4*)(vsrc + 12);
    uint4v w0, w1;
    w0[0] = pk_bf16(a0[0], a0[1]); w0[1] = pk_bf16(a0[2], a0[3]);
    w0[2] = pk_bf16(a1[0], a1[1]); w0[3] = pk_bf16(a1[2], a1[3]);
    w1[0] = pk_bf16(a2[0], a2[1]); w1[1] = pk_bf16(a2[2], a2[3]);
    w1[2] = pk_bf16(a3[0], a3[1]); w1[3] = pk_bf16(a3[2], a3[3]);
    *(uint4v*)&k_lds[0][srow][scol ^ ssw]       = w0;
    *(uint4v*)&k_lds[0][srow][(scol + 8) ^ ssw] = w1;
    f32x4 bb[4] = { b0, b1, b2, b3 };
    #pragma unroll
    for (int c = 0; c < 4; ++c)
      #pragma unroll
      for (int e = 0; e < 4; ++e) {
        const int dd = scol + 4 * c + e;
        vt_lds[0][dd][srow ^ (vswz(dd) << 3)] = (__bf16)bb[c][e];
      }
  }
  __syncthreads();

  for (int t = 0; t < nkb; ++t) {
    const int cur   = t & 1;
    const int kbase = t * 64;
    const bool pre  = (t + 1 < nkb);

    // ---- issue next tile's global loads EARLY (in flight during compute) ----
    f32x4 a0, a1, a2, a3, b0, b1, b2, b3;
    if (pre) {
      const float* ksrc = Kb + (size_t)(kbase + 64 + srow) * Dc + scol;
      a0 = *(const f32x4*)ksrc;
      a1 = *(const f32x4*)(ksrc + 4);
      a2 = *(const f32x4*)(ksrc + 8);
      a3 = *(const f32x4*)(ksrc + 12);
      const float* vsrc = Vb + (size_t)(kbase + 64 + srow) * Dc + scol;
      b0 = *(const f32x4*)vsrc;
      b1 = *(const f32x4*)(vsrc + 4);
      b2 = *(const f32x4*)(vsrc + 8);
      b3 = *(const f32x4*)(vsrc + 12);
    }

    if (kbase <= wq + 31) {   // wave-active (no barriers inside)
      const __bf16 (*kc)[64] = k_lds[cur];
      const __bf16 (*vc)[64] = vt_lds[cur];

      // ---- S^T = K * Q^T ----
      f32x16 s0, s1;
      #pragma unroll
      for (int i = 0; i < 16; ++i) { s0[i] = 0.f; s1[i] = 0.f; }
      const int ksw = (l31 & 7) << 3;
      #pragma unroll
      for (int s = 0; s < 4; ++s) {
        bf16x8 kf = *(const bf16x8*)&kc[l31][(s * 16 + hi * 8) ^ ksw];
        s0 = __builtin_amdgcn_mfma_f32_32x32x16_bf16(kf, qf[s], s0, 0, 0, 0);
      }
      #pragma unroll
      for (int s = 0; s < 4; ++s) {
        bf16x8 kf = *(const bf16x8*)&kc[32 + l31][(s * 16 + hi * 8) ^ ksw];
        s1 = __builtin_amdgcn_mfma_f32_32x32x16_bf16(kf, qf[s], s1, 0, 0, 0);
      }

      // ---- causal mask (diagonal tiles only) ----
      if (kbase + 63 > wq) {
        const int q   = wq + l31;
        const int dq0 = q - (kbase + 4 * hi);
        const int dq1 = q - (kbase + 32 + 4 * hi);
        #pragma unroll
        for (int i = 0; i < 16; ++i) {
          const int off = (i & 3) + 8 * (i >> 2);
          if (off > dq0) s0[i] = -1e30f;
          if (off > dq1) s1[i] = -1e30f;
        }
      }

      // ---- in-register online softmax (exp2 domain) ----
      float pmax = s0[0];
      #pragma unroll
      for (int i = 1; i < 16; ++i) pmax = fmaxf(pmax, s0[i]);
      #pragma unroll
      for (int i = 0; i < 16; ++i) pmax = fmaxf(pmax, s1[i]);
      pmax = xhalf_max(pmax);
      const float mnew = fmaxf(m, pmax);
      const float corr = exp2_hw(m - mnew);
      m = mnew;
      #pragma unroll
      for (int i = 0; i < 16; ++i) {
        s0[i] = exp2_hw(s0[i] - mnew);
        s1[i] = exp2_hw(s1[i] - mnew);
      }
      float rs = 0.f;
      #pragma unroll
      for (int i = 0; i < 16; ++i) rs += s0[i] + s1[i];
      rs = xhalf_sum(rs);
      l = l * corr + rs;
      #pragma unroll
      for (int i = 0; i < 16; ++i) { o0[i] *= corr; o1[i] *= corr; }

      // ---- P -> PV B-fragments: 16 cvt_pk + 8 permlane32_swap ----
      uint4v wv;
      unsigned t0, t1, t2, t3;
      t0 = pk_bf16(s0[0], s0[1]);  t1 = pk_bf16(s0[2], s0[3]);
      t2 = pk_bf16(s0[4], s0[5]);  t3 = pk_bf16(s0[6], s0[7]);
      pl32swap(t0, t2); pl32swap(t1, t3);
      wv[0] = t0; wv[1] = t1; wv[2] = t2; wv[3] = t3;
      const bf16x8 pf0 = __builtin_bit_cast(bf16x8, wv);
      t0 = pk_bf16(s0[8], s0[9]);   t1 = pk_bf16(s0[10], s0[11]);
      t2 = pk_bf16(s0[12], s0[13]); t3 = pk_bf16(s0[14], s0[15]);
      pl32swap(t0, t2); pl32swap(t1, t3);
      wv[0] = t0; wv[1] = t1; wv[2] = t2; wv[3] = t3;
      const bf16x8 pf1 = __builtin_bit_cast(bf16x8, wv);
      t0 = pk_bf16(s1[0], s1[1]);  t1 = pk_bf16(s1[2], s1[3]);
      t2 = pk_bf16(s1[4], s1[5]);  t3 = pk_bf16(s1[6], s1[7]);
      pl32swap(t0, t2); pl32swap(t1, t3);
      wv[0] = t0; wv[1] = t1; wv[2] = t2; wv[3] = t3;
      const bf16x8 pf2 = __builtin_bit_cast(bf16x8, wv);
      t0 = pk_bf16(s1[8], s1[9]);   t1 = pk_bf16(s1[10], s1[11]);
      t2 = pk_bf16(s1[12], s1[13]); t3 = pk_bf16(s1[14], s1[15]);
      pl32swap(t0, t2); pl32swap(t1, t3);
      wv[0] = t0; wv[1] = t1; wv[2] = t2; wv[3] = t3;
      const bf16x8 pf3 = __builtin_bit_cast(bf16x8, wv);

      // ---- O^T += V^T * P ----
      const int vd0 = l31, vd1 = 32 + l31;
      const int vs0 = vswz(vd0) << 3, vs1 = vswz(vd1) << 3;
      bf16x8 vf;
      vf = *(const bf16x8*)&vc[vd0][(hi * 8) ^ vs0];
      o0 = __builtin_amdgcn_mfma_f32_32x32x16_bf16(vf, pf0, o0, 0, 0, 0);
      vf = *(const bf16x8*)&vc[vd0][(16 + hi * 8) ^ vs0];
      o0 = __builtin_amdgcn_mfma_f32_32x32x16_bf16(vf, pf1, o0, 0, 0, 0);
      vf = *(const bf16x8*)&vc[vd0][(32 + hi * 8) ^ vs0];
      o0 = __builtin_amdgcn_mfma_f32_32x32x16_bf16(vf, pf2, o0, 0, 0, 0);
      vf = *(const bf16x8*)&vc[vd0][(48 + hi * 8) ^ vs0];
      o0 = __builtin_amdgcn_mfma_f32_32x32x16_bf16(vf, pf3, o0, 0, 0, 0);
      vf = *(const bf16x8*)&vc[vd1][(hi * 8) ^ vs1];
      o1 = __builtin_amdgcn_mfma_f32_32x32x16_bf16(vf, pf0, o1, 0, 0, 0);
      vf = *(const bf16x8*)&vc[vd1][(16 + hi * 8) ^ vs1];
      o1 = __builtin_amdgcn_mfma_f32_32x32x16_bf16(vf, pf1, o1, 0, 0, 0);
      vf = *(const bf16x8*)&vc[vd1][(32 + hi * 8) ^ vs1];
      o1 = __builtin_amdgcn_mfma_f32_32x32x16_bf16(vf, pf2, o1, 0, 0, 0);
      vf = *(const bf16x8*)&vc[vd1][(48 + hi * 8) ^ vs1];
      o1 = __builtin_amdgcn_mfma_f32_32x32x16_bf16(vf, pf3, o1, 0, 0, 0);
    }

    // ---- STAGE_WRITE for t+1 (vmcnt wait lands here, after compute) ----
    if (pre) {
      const int nxt = cur ^ 1;
      uint4v w0, w1;
      w0[0] = pk_bf16(a0[0], a0[1]); w0[1] = pk_bf16(a0[2], a0[3]);
      w0[2] = pk_bf16(a1[0], a1[1]); w0[3] = pk_bf16(a1[2], a1[3]);
      w1[0] = pk_bf16(a2[0], a2[1]); w1[1] = pk_bf16(a2[2], a2[3]);
      w1[2] = pk_bf16(a3[0], a3[1]); w1[3] = pk_bf16(a3[2], a3[3]);
      *(uint4v*)&k_lds[nxt][srow][scol ^ ssw]       = w0;
      *(uint4v*)&k_lds[nxt][srow][(scol + 8) ^ ssw] = w1;
      f32x4 bb[4] = { b0, b1, b2, b3 };
      #pragma unroll
      for (int c = 0; c < 4; ++c)
        #pragma unroll
        for (int e = 0; e < 4; ++e) {
          const int dd = scol + 4 * c + e;
          vt_lds[nxt][dd][srow ^ (vswz(dd) << 3)] = (__bf16)bb[c][e];
        }
    }
    __syncthreads();
  }

  // ---- epilogue: O^T regs -> rows of O ----
  const float inv = 1.0f / l;
  float* orow = Ob + (size_t)(wq + l31) * Dc;
  #pragma unroll
  for (int b = 0; b < 4; ++b) {
    f32x4 u0, u1;
    #pragma unroll
    for (int e = 0; e < 4; ++e) { u0[e] = o0[4 * b + e] * inv; u1[e] = o1[4 * b + e] * inv; }
    *(f32x4*)(orow + 8 * b + 4 * hi)      = u0;
    *(f32x4*)(orow + 32 + 8 * b + 4 * hi) = u1;
  }
}

}  // namespace

extern "C" void kernel_launch(void* const* d_in, const int* in_sizes, int n_in,
                              void* d_out, int out_size, void* d_ws, size_t ws_size,
                              hipStream_t stream) {
  const float* q = (const float*)d_in[0];
  const float* k = (const float*)d_in[1];
  const float* v = (const float*)d_in[2];
  // d_in[3] (triu mask) applied analytically.
  float* o = (float*)d_out;
  dim3 grid(16 * Bc * Hc);  // 1024 single-panel blocks, LPT dispatch order
  fattn_kernel<<<grid, dim3(256), 0, stream>>>(q, k, v, o);
}

// Round 7
// 97.979 us; speedup vs baseline: 1.8211x; 1.8211x over previous
//
#include <hip/hip_runtime.h>
#include <hip/hip_bf16.h>

namespace {

constexpr int Bc = 4, Hc = 16, Sc = 2048, Dc = 64;

using bf16x2 = __attribute__((ext_vector_type(2))) __bf16;
using bf16x8 = __attribute__((ext_vector_type(8))) __bf16;
using f32x4  = __attribute__((ext_vector_type(4))) float;
using f32x16 = __attribute__((ext_vector_type(16))) float;
using uint4v = __attribute__((ext_vector_type(4))) unsigned int;

__device__ __forceinline__ float exp2_hw(float x) {
#if __has_builtin(__builtin_amdgcn_exp2f)
  return __builtin_amdgcn_exp2f(x);
#else
  return exp2f(x);
#endif
}

__device__ __forceinline__ unsigned pk_bf16(float a, float b) {
  bf16x2 t = { (__bf16)a, (__bf16)b };
  return __builtin_bit_cast(unsigned, t);
}

// v_permlane32_swap_b32 a,b with s_nop hazard padding (raw asm bypasses the
// post-RA hazard recognizer). Operands must be DISTINCT live values.
__device__ __forceinline__ void pl32swap(unsigned& a, unsigned& b) {
  asm volatile("s_nop 1\n\tv_permlane32_swap_b32 %0, %1\n\ts_nop 1"
               : "+v"(a), "+v"(b));
}
// Early-clobber dual-mov guarantees the two swap operands sit in distinct regs
// (round-3 lesson: copies of one SSA value may share a VGPR).
__device__ __forceinline__ void xhalf_pair(float x, float& lo, float& hi) {
  unsigned a, b;
  asm volatile("v_mov_b32 %0, %2\n\t"
               "v_mov_b32 %1, %2\n\t"
               "s_nop 1\n\t"
               "v_permlane32_swap_b32 %0, %1\n\t"
               "s_nop 1"
               : "=&v"(a), "=&v"(b)
               : "v"(x));
  lo = __builtin_bit_cast(float, a);
  hi = __builtin_bit_cast(float, b);
}
__device__ __forceinline__ float xhalf_max(float x) {
  float lo, hi; xhalf_pair(x, lo, hi); return fmaxf(lo, hi);
}
__device__ __forceinline__ float xhalf_sum(float x) {
  float lo, hi; xhalf_pair(x, lo, hi); return lo + hi;
}

__device__ __forceinline__ int vswz(int d) { return ((d >> 4) ^ d) & 7; }

// Block = 8 waves x 32 q-rows = ONE 256-row q-panel (tiles = 4P+4), 512 thr.
// Grid = 8 panels x 64 bh = 512 blocks -> 2 blocks/CU co-resident
// = 16 waves/CU = 4 waves/SIMD (VGPR ~104 allows it; round-6 lesson: do NOT
// cap the allocator below ~104 -> launch_bounds(512,2) only).
// Static per-CU balance: per-XCD dispatch sequence s pairs P=7-(s>>2) with
// P=(s>>2)-8 on the same CU (s and s+32) -> every CU hosts P-sum 7 = 36 tiles.
// K/V staging shared by 8 waves (half the per-thread staging work of r5).
__global__ __launch_bounds__(512, 2)
void fattn_kernel(const float* __restrict__ Q, const float* __restrict__ K,
                  const float* __restrict__ V, float* __restrict__ O) {
  const int tid  = threadIdx.x;
  const int wid  = tid >> 6;      // 0..7
  const int lane = tid & 63;
  const int l31  = lane & 31;
  const int hi   = lane >> 5;

  // d -> (xcd, bh, P): bijective; CU-sets balanced by construction.
  const int d   = blockIdx.x;
  const int xcd = d & 7;
  const int s   = d >> 3;                                   // 0..63 per XCD
  const int P   = (s < 32) ? (7 - (s >> 2)) : ((s >> 2) - 8);
  const int bhl = (s < 32) ? (s & 3) : ((s & 3) + 4);
  const int bh  = xcd * 8 + bhl;

  const int qb  = P * 256;
  const int wq  = qb + wid * 32;
  const int nkb = 4 * P + 4;

  const size_t base = (size_t)bh * (Sc * Dc);
  const float* Qb = Q + base;
  const float* Kb = K + base;
  const float* Vb = V + base;
  float*       Ob = O + base;

  __shared__ __align__(16) __bf16 k_lds[2][64][64];   // K[k][d],  col ^= (k&7)<<3
  __shared__ __align__(16) __bf16 vt_lds[2][64][64];  // V^T[d][k], k ^= vswz(d)<<3

  const int srow = tid >> 3;         // staging row 0..63
  const int scol = (tid & 7) * 8;    // staging col chunk (8 floats)
  const int ssw  = (srow & 7) << 3;

  constexpr float QSC = 0.125f * 1.44269504088896f;  // 1/sqrt(D) * log2(e)

  // ---- Q fragment: lane holds Q[wq + l31][d = s*16 + hi*8 + j] ----
  bf16x8 qf[4];
  {
    const float* qrow = Qb + (size_t)(wq + l31) * Dc;
    #pragma unroll
    for (int ss = 0; ss < 4; ++ss) {
      const float* src = qrow + ss * 16 + hi * 8;
      f32x4 a0 = *(const f32x4*)src;
      f32x4 a1 = *(const f32x4*)(src + 4);
      uint4v wv;
      wv[0] = pk_bf16(a0[0] * QSC, a0[1] * QSC);
      wv[1] = pk_bf16(a0[2] * QSC, a0[3] * QSC);
      wv[2] = pk_bf16(a1[0] * QSC, a1[1] * QSC);
      wv[3] = pk_bf16(a1[2] * QSC, a1[3] * QSC);
      qf[ss] = __builtin_bit_cast(bf16x8, wv);
    }
  }

  f32x16 o0, o1;   // O^T: col q = l31; row d = dh*32 + (i&3) + 8*(i>>2) + 4*hi
  #pragma unroll
  for (int i = 0; i < 16; ++i) { o0[i] = 0.f; o1[i] = 0.f; }
  float m = -1e30f, l = 0.f;

  // ---- prologue: stage tile 0 into buffer 0 (8 K-floats + 8 V-floats/thr) ----
  {
    const float* ksrc = Kb + (size_t)srow * Dc + scol;
    f32x4 a0 = *(const f32x4*)ksrc;
    f32x4 a1 = *(const f32x4*)(ksrc + 4);
    const float* vsrc = Vb + (size_t)srow * Dc + scol;
    f32x4 b0 = *(const f32x4*)vsrc;
    f32x4 b1 = *(const f32x4*)(vsrc + 4);
    uint4v w0;
    w0[0] = pk_bf16(a0[0], a0[1]); w0[1] = pk_bf16(a0[2], a0[3]);
    w0[2] = pk_bf16(a1[0], a1[1]); w0[3] = pk_bf16(a1[2], a1[3]);
    *(uint4v*)&k_lds[0][srow][scol ^ ssw] = w0;
    f32x4 bb[2] = { b0, b1 };
    #pragma unroll
    for (int c = 0; c < 2; ++c)
      #pragma unroll
      for (int e = 0; e < 4; ++e) {
        const int dd = scol + 4 * c + e;
        vt_lds[0][dd][srow ^ (vswz(dd) << 3)] = (__bf16)bb[c][e];
      }
  }
  __syncthreads();

  for (int t = 0; t < nkb; ++t) {
    const int cur   = t & 1;
    const int kbase = t * 64;
    const bool pre  = (t + 1 < nkb);

    // ---- issue next tile's global loads EARLY (in flight during compute) ----
    f32x4 a0, a1, b0, b1;
    if (pre) {
      const float* ksrc = Kb + (size_t)(kbase + 64 + srow) * Dc + scol;
      a0 = *(const f32x4*)ksrc;
      a1 = *(const f32x4*)(ksrc + 4);
      const float* vsrc = Vb + (size_t)(kbase + 64 + srow) * Dc + scol;
      b0 = *(const f32x4*)vsrc;
      b1 = *(const f32x4*)(vsrc + 4);
    }

    if (kbase <= wq + 31) {   // wave-active (no barriers inside)
      const __bf16 (*kc)[64] = k_lds[cur];
      const __bf16 (*vc)[64] = vt_lds[cur];

      // ---- S^T = K * Q^T ----
      f32x16 s0, s1;
      #pragma unroll
      for (int i = 0; i < 16; ++i) { s0[i] = 0.f; s1[i] = 0.f; }
      const int ksw = (l31 & 7) << 3;
      #pragma unroll
      for (int ss = 0; ss < 4; ++ss) {
        bf16x8 kf = *(const bf16x8*)&kc[l31][(ss * 16 + hi * 8) ^ ksw];
        s0 = __builtin_amdgcn_mfma_f32_32x32x16_bf16(kf, qf[ss], s0, 0, 0, 0);
      }
      #pragma unroll
      for (int ss = 0; ss < 4; ++ss) {
        bf16x8 kf = *(const bf16x8*)&kc[32 + l31][(ss * 16 + hi * 8) ^ ksw];
        s1 = __builtin_amdgcn_mfma_f32_32x32x16_bf16(kf, qf[ss], s1, 0, 0, 0);
      }

      // ---- causal mask (diagonal tiles only) ----
      if (kbase + 63 > wq) {
        const int q   = wq + l31;
        const int dq0 = q - (kbase + 4 * hi);
        const int dq1 = q - (kbase + 32 + 4 * hi);
        #pragma unroll
        for (int i = 0; i < 16; ++i) {
          const int off = (i & 3) + 8 * (i >> 2);
          if (off > dq0) s0[i] = -1e30f;
          if (off > dq1) s1[i] = -1e30f;
        }
      }

      // ---- in-register online softmax (exp2 domain) ----
      float pmax = s0[0];
      #pragma unroll
      for (int i = 1; i < 16; ++i) pmax = fmaxf(pmax, s0[i]);
      #pragma unroll
      for (int i = 0; i < 16; ++i) pmax = fmaxf(pmax, s1[i]);
      pmax = xhalf_max(pmax);
      const float mnew = fmaxf(m, pmax);
      const float corr = exp2_hw(m - mnew);
      m = mnew;
      #pragma unroll
      for (int i = 0; i < 16; ++i) {
        s0[i] = exp2_hw(s0[i] - mnew);
        s1[i] = exp2_hw(s1[i] - mnew);
      }
      float rs = 0.f;
      #pragma unroll
      for (int i = 0; i < 16; ++i) rs += s0[i] + s1[i];
      rs = xhalf_sum(rs);
      l = l * corr + rs;
      #pragma unroll
      for (int i = 0; i < 16; ++i) { o0[i] *= corr; o1[i] *= corr; }

      // ---- P -> PV B-fragments: 16 cvt_pk + 8 permlane32_swap ----
      uint4v wv;
      unsigned t0, t1, t2, t3;
      t0 = pk_bf16(s0[0], s0[1]);  t1 = pk_bf16(s0[2], s0[3]);
      t2 = pk_bf16(s0[4], s0[5]);  t3 = pk_bf16(s0[6], s0[7]);
      pl32swap(t0, t2); pl32swap(t1, t3);
      wv[0] = t0; wv[1] = t1; wv[2] = t2; wv[3] = t3;
      const bf16x8 pf0 = __builtin_bit_cast(bf16x8, wv);
      t0 = pk_bf16(s0[8], s0[9]);   t1 = pk_bf16(s0[10], s0[11]);
      t2 = pk_bf16(s0[12], s0[13]); t3 = pk_bf16(s0[14], s0[15]);
      pl32swap(t0, t2); pl32swap(t1, t3);
      wv[0] = t0; wv[1] = t1; wv[2] = t2; wv[3] = t3;
      const bf16x8 pf1 = __builtin_bit_cast(bf16x8, wv);
      t0 = pk_bf16(s1[0], s1[1]);  t1 = pk_bf16(s1[2], s1[3]);
      t2 = pk_bf16(s1[4], s1[5]);  t3 = pk_bf16(s1[6], s1[7]);
      pl32swap(t0, t2); pl32swap(t1, t3);
      wv[0] = t0; wv[1] = t1; wv[2] = t2; wv[3] = t3;
      const bf16x8 pf2 = __builtin_bit_cast(bf16x8, wv);
      t0 = pk_bf16(s1[8], s1[9]);   t1 = pk_bf16(s1[10], s1[11]);
      t2 = pk_bf16(s1[12], s1[13]); t3 = pk_bf16(s1[14], s1[15]);
      pl32swap(t0, t2); pl32swap(t1, t3);
      wv[0] = t0; wv[1] = t1; wv[2] = t2; wv[3] = t3;
      const bf16x8 pf3 = __builtin_bit_cast(bf16x8, wv);

      // ---- O^T += V^T * P ----
      const int vd0 = l31, vd1 = 32 + l31;
      const int vs0 = vswz(vd0) << 3, vs1 = vswz(vd1) << 3;
      bf16x8 vf;
      vf = *(const bf16x8*)&vc[vd0][(hi * 8) ^ vs0];
      o0 = __builtin_amdgcn_mfma_f32_32x32x16_bf16(vf, pf0, o0, 0, 0, 0);
      vf = *(const bf16x8*)&vc[vd0][(16 + hi * 8) ^ vs0];
      o0 = __builtin_amdgcn_mfma_f32_32x32x16_bf16(vf, pf1, o0, 0, 0, 0);
      vf = *(const bf16x8*)&vc[vd0][(32 + hi * 8) ^ vs0];
      o0 = __builtin_amdgcn_mfma_f32_32x32x16_bf16(vf, pf2, o0, 0, 0, 0);
      vf = *(const bf16x8*)&vc[vd0][(48 + hi * 8) ^ vs0];
      o0 = __builtin_amdgcn_mfma_f32_32x32x16_bf16(vf, pf3, o0, 0, 0, 0);
      vf = *(const bf16x8*)&vc[vd1][(hi * 8) ^ vs1];
      o1 = __builtin_amdgcn_mfma_f32_32x32x16_bf16(vf, pf0, o1, 0, 0, 0);
      vf = *(const bf16x8*)&vc[vd1][(16 + hi * 8) ^ vs1];
      o1 = __builtin_amdgcn_mfma_f32_32x32x16_bf16(vf, pf1, o1, 0, 0, 0);
      vf = *(const bf16x8*)&vc[vd1][(32 + hi * 8) ^ vs1];
      o1 = __builtin_amdgcn_mfma_f32_32x32x16_bf16(vf, pf2, o1, 0, 0, 0);
      vf = *(const bf16x8*)&vc[vd1][(48 + hi * 8) ^ vs1];
      o1 = __builtin_amdgcn_mfma_f32_32x32x16_bf16(vf, pf3, o1, 0, 0, 0);
    }

    // ---- STAGE_WRITE for t+1 (vmcnt wait lands here, after compute) ----
    if (pre) {
      const int nxt = cur ^ 1;
      uint4v w0;
      w0[0] = pk_bf16(a0[0], a0[1]); w0[1] = pk_bf16(a0[2], a0[3]);
      w0[2] = pk_bf16(a1[0], a1[1]); w0[3] = pk_bf16(a1[2], a1[3]);
      *(uint4v*)&k_lds[nxt][srow][scol ^ ssw] = w0;
      f32x4 bb[2] = { b0, b1 };
      #pragma unroll
      for (int c = 0; c < 2; ++c)
        #pragma unroll
        for (int e = 0; e < 4; ++e) {
          const int dd = scol + 4 * c + e;
          vt_lds[nxt][dd][srow ^ (vswz(dd) << 3)] = (__bf16)bb[c][e];
        }
    }
    __syncthreads();
  }

  // ---- epilogue: O^T regs -> rows of O ----
  const float inv = 1.0f / l;
  float* orow = Ob + (size_t)(wq + l31) * Dc;
  #pragma unroll
  for (int b = 0; b < 4; ++b) {
    f32x4 u0, u1;
    #pragma unroll
    for (int e = 0; e < 4; ++e) { u0[e] = o0[4 * b + e] * inv; u1[e] = o1[4 * b + e] * inv; }
    *(f32x4*)(orow + 8 * b + 4 * hi)      = u0;
    *(f32x4*)(orow + 32 + 8 * b + 4 * hi) = u1;
  }
}

}  // namespace

extern "C" void kernel_launch(void* const* d_in, const int* in_sizes, int n_in,
                              void* d_out, int out_size, void* d_ws, size_t ws_size,
                              hipStream_t stream) {
  const float* q = (const float*)d_in[0];
  const float* k = (const float*)d_in[1];
  const float* v = (const float*)d_in[2];
  // d_in[3] (triu mask) applied analytically.
  float* o = (float*)d_out;
  fattn_kernel<<<dim3(512), dim3(512), 0, stream>>>(q, k, v, o);
}

// Round 8
// 89.791 us; speedup vs baseline: 1.9871x; 1.0912x over previous
//
#include <hip/hip_runtime.h>
#include <hip/hip_bf16.h>

namespace {

constexpr int Bc = 4, Hc = 16, Sc = 2048, Dc = 64;

using bf16x2 = __attribute__((ext_vector_type(2))) __bf16;
using bf16x8 = __attribute__((ext_vector_type(8))) __bf16;
using f32x4  = __attribute__((ext_vector_type(4))) float;
using f32x16 = __attribute__((ext_vector_type(16))) float;
using uint4v = __attribute__((ext_vector_type(4))) unsigned int;

__device__ __forceinline__ float exp2_hw(float x) {
#if __has_builtin(__builtin_amdgcn_exp2f)
  return __builtin_amdgcn_exp2f(x);
#else
  return exp2f(x);
#endif
}

__device__ __forceinline__ unsigned pk_bf16(float a, float b) {
  bf16x2 t = { (__bf16)a, (__bf16)b };
  return __builtin_bit_cast(unsigned, t);
}

// v_permlane32_swap_b32 a,b with s_nop hazard padding (raw asm bypasses the
// post-RA hazard recognizer). Operands must be DISTINCT live values.
__device__ __forceinline__ void pl32swap(unsigned& a, unsigned& b) {
  asm volatile("s_nop 1\n\tv_permlane32_swap_b32 %0, %1\n\ts_nop 1"
               : "+v"(a), "+v"(b));
}
// Early-clobber dual-mov guarantees the two swap operands sit in distinct regs
// (round-3 lesson: copies of one SSA value may share a VGPR).
__device__ __forceinline__ void xhalf_pair(float x, float& lo, float& hi) {
  unsigned a, b;
  asm volatile("v_mov_b32 %0, %2\n\t"
               "v_mov_b32 %1, %2\n\t"
               "s_nop 1\n\t"
               "v_permlane32_swap_b32 %0, %1\n\t"
               "s_nop 1"
               : "=&v"(a), "=&v"(b)
               : "v"(x));
  lo = __builtin_bit_cast(float, a);
  hi = __builtin_bit_cast(float, b);
}
__device__ __forceinline__ float xhalf_max(float x) {
  float lo, hi; xhalf_pair(x, lo, hi); return fmaxf(lo, hi);
}
__device__ __forceinline__ float xhalf_sum(float x) {
  float lo, hi; xhalf_pair(x, lo, hi); return lo + hi;
}

__device__ __forceinline__ int vswz(int d) { return ((d >> 4) ^ d) & 7; }

// Block = 8 waves x 32 q-rows = ONE 256-row q-panel (tiles = 4P+4), 512 thr.
// Grid = 8 panels x 64 bh = 512 blocks -> 2 blocks/CU co-resident
// = 16 waves/CU = 4 waves/SIMD.
// __launch_bounds__(512, 4): second arg is WAVES PER SIMD (round-7 lesson:
// (512,2) meant 1 block/CU, not 2). 4 waves/SIMD caps VGPR at 128; free-choice
// usage is 76, so codegen is unchanged — pure occupancy doubling.
// Static per-CU balance: per-XCD dispatch sequence s pairs P=7-(s>>2) with
// P=(s>>2)-8 on the same CU (s and s+32) -> every CU hosts P-sum 7 = 36 tiles.
__global__ __launch_bounds__(512, 4)
void fattn_kernel(const float* __restrict__ Q, const float* __restrict__ K,
                  const float* __restrict__ V, float* __restrict__ O) {
  const int tid  = threadIdx.x;
  const int wid  = tid >> 6;      // 0..7
  const int lane = tid & 63;
  const int l31  = lane & 31;
  const int hi   = lane >> 5;

  // d -> (xcd, bh, P): bijective; CU-sets balanced by construction.
  const int d   = blockIdx.x;
  const int xcd = d & 7;
  const int s   = d >> 3;                                   // 0..63 per XCD
  const int P   = (s < 32) ? (7 - (s >> 2)) : ((s >> 2) - 8);
  const int bhl = (s < 32) ? (s & 3) : ((s & 3) + 4);
  const int bh  = xcd * 8 + bhl;

  const int qb  = P * 256;
  const int wq  = qb + wid * 32;
  const int nkb = 4 * P + 4;

  const size_t base = (size_t)bh * (Sc * Dc);
  const float* Qb = Q + base;
  const float* Kb = K + base;
  const float* Vb = V + base;
  float*       Ob = O + base;

  __shared__ __align__(16) __bf16 k_lds[2][64][64];   // K[k][d],  col ^= (k&7)<<3
  __shared__ __align__(16) __bf16 vt_lds[2][64][64];  // V^T[d][k], k ^= vswz(d)<<3

  const int srow = tid >> 3;         // staging row 0..63
  const int scol = (tid & 7) * 8;    // staging col chunk (8 floats)
  const int ssw  = (srow & 7) << 3;

  constexpr float QSC = 0.125f * 1.44269504088896f;  // 1/sqrt(D) * log2(e)

  // ---- Q fragment: lane holds Q[wq + l31][d = s*16 + hi*8 + j] ----
  bf16x8 qf[4];
  {
    const float* qrow = Qb + (size_t)(wq + l31) * Dc;
    #pragma unroll
    for (int ss = 0; ss < 4; ++ss) {
      const float* src = qrow + ss * 16 + hi * 8;
      f32x4 a0 = *(const f32x4*)src;
      f32x4 a1 = *(const f32x4*)(src + 4);
      uint4v wv;
      wv[0] = pk_bf16(a0[0] * QSC, a0[1] * QSC);
      wv[1] = pk_bf16(a0[2] * QSC, a0[3] * QSC);
      wv[2] = pk_bf16(a1[0] * QSC, a1[1] * QSC);
      wv[3] = pk_bf16(a1[2] * QSC, a1[3] * QSC);
      qf[ss] = __builtin_bit_cast(bf16x8, wv);
    }
  }

  f32x16 o0, o1;   // O^T: col q = l31; row d = dh*32 + (i&3) + 8*(i>>2) + 4*hi
  #pragma unroll
  for (int i = 0; i < 16; ++i) { o0[i] = 0.f; o1[i] = 0.f; }
  float m = -1e30f, l = 0.f;

  // ---- prologue: stage tile 0 into buffer 0 (8 K-floats + 8 V-floats/thr) ----
  {
    const float* ksrc = Kb + (size_t)srow * Dc + scol;
    f32x4 a0 = *(const f32x4*)ksrc;
    f32x4 a1 = *(const f32x4*)(ksrc + 4);
    const float* vsrc = Vb + (size_t)srow * Dc + scol;
    f32x4 b0 = *(const f32x4*)vsrc;
    f32x4 b1 = *(const f32x4*)(vsrc + 4);
    uint4v w0;
    w0[0] = pk_bf16(a0[0], a0[1]); w0[1] = pk_bf16(a0[2], a0[3]);
    w0[2] = pk_bf16(a1[0], a1[1]); w0[3] = pk_bf16(a1[2], a1[3]);
    *(uint4v*)&k_lds[0][srow][scol ^ ssw] = w0;
    f32x4 bb[2] = { b0, b1 };
    #pragma unroll
    for (int c = 0; c < 2; ++c)
      #pragma unroll
      for (int e = 0; e < 4; ++e) {
        const int dd = scol + 4 * c + e;
        vt_lds[0][dd][srow ^ (vswz(dd) << 3)] = (__bf16)bb[c][e];
      }
  }
  __syncthreads();

  for (int t = 0; t < nkb; ++t) {
    const int cur   = t & 1;
    const int kbase = t * 64;
    const bool pre  = (t + 1 < nkb);

    // ---- issue next tile's global loads EARLY (in flight during compute) ----
    f32x4 a0, a1, b0, b1;
    if (pre) {
      const float* ksrc = Kb + (size_t)(kbase + 64 + srow) * Dc + scol;
      a0 = *(const f32x4*)ksrc;
      a1 = *(const f32x4*)(ksrc + 4);
      const float* vsrc = Vb + (size_t)(kbase + 64 + srow) * Dc + scol;
      b0 = *(const f32x4*)vsrc;
      b1 = *(const f32x4*)(vsrc + 4);
    }

    if (kbase <= wq + 31) {   // wave-active (no barriers inside)
      const __bf16 (*kc)[64] = k_lds[cur];
      const __bf16 (*vc)[64] = vt_lds[cur];

      // ---- S^T = K * Q^T ----
      f32x16 s0, s1;
      #pragma unroll
      for (int i = 0; i < 16; ++i) { s0[i] = 0.f; s1[i] = 0.f; }
      const int ksw = (l31 & 7) << 3;
      #pragma unroll
      for (int ss = 0; ss < 4; ++ss) {
        bf16x8 kf = *(const bf16x8*)&kc[l31][(ss * 16 + hi * 8) ^ ksw];
        s0 = __builtin_amdgcn_mfma_f32_32x32x16_bf16(kf, qf[ss], s0, 0, 0, 0);
      }
      #pragma unroll
      for (int ss = 0; ss < 4; ++ss) {
        bf16x8 kf = *(const bf16x8*)&kc[32 + l31][(ss * 16 + hi * 8) ^ ksw];
        s1 = __builtin_amdgcn_mfma_f32_32x32x16_bf16(kf, qf[ss], s1, 0, 0, 0);
      }

      // ---- causal mask (diagonal tiles only) ----
      if (kbase + 63 > wq) {
        const int q   = wq + l31;
        const int dq0 = q - (kbase + 4 * hi);
        const int dq1 = q - (kbase + 32 + 4 * hi);
        #pragma unroll
        for (int i = 0; i < 16; ++i) {
          const int off = (i & 3) + 8 * (i >> 2);
          if (off > dq0) s0[i] = -1e30f;
          if (off > dq1) s1[i] = -1e30f;
        }
      }

      // ---- in-register online softmax (exp2 domain) ----
      float pmax = s0[0];
      #pragma unroll
      for (int i = 1; i < 16; ++i) pmax = fmaxf(pmax, s0[i]);
      #pragma unroll
      for (int i = 0; i < 16; ++i) pmax = fmaxf(pmax, s1[i]);
      pmax = xhalf_max(pmax);
      const float mnew = fmaxf(m, pmax);
      const float corr = exp2_hw(m - mnew);
      m = mnew;
      #pragma unroll
      for (int i = 0; i < 16; ++i) {
        s0[i] = exp2_hw(s0[i] - mnew);
        s1[i] = exp2_hw(s1[i] - mnew);
      }
      float rs = 0.f;
      #pragma unroll
      for (int i = 0; i < 16; ++i) rs += s0[i] + s1[i];
      rs = xhalf_sum(rs);
      l = l * corr + rs;
      #pragma unroll
      for (int i = 0; i < 16; ++i) { o0[i] *= corr; o1[i] *= corr; }

      // ---- P -> PV B-fragments: 16 cvt_pk + 8 permlane32_swap ----
      uint4v wv;
      unsigned t0, t1, t2, t3;
      t0 = pk_bf16(s0[0], s0[1]);  t1 = pk_bf16(s0[2], s0[3]);
      t2 = pk_bf16(s0[4], s0[5]);  t3 = pk_bf16(s0[6], s0[7]);
      pl32swap(t0, t2); pl32swap(t1, t3);
      wv[0] = t0; wv[1] = t1; wv[2] = t2; wv[3] = t3;
      const bf16x8 pf0 = __builtin_bit_cast(bf16x8, wv);
      t0 = pk_bf16(s0[8], s0[9]);   t1 = pk_bf16(s0[10], s0[11]);
      t2 = pk_bf16(s0[12], s0[13]); t3 = pk_bf16(s0[14], s0[15]);
      pl32swap(t0, t2); pl32swap(t1, t3);
      wv[0] = t0; wv[1] = t1; wv[2] = t2; wv[3] = t3;
      const bf16x8 pf1 = __builtin_bit_cast(bf16x8, wv);
      t0 = pk_bf16(s1[0], s1[1]);  t1 = pk_bf16(s1[2], s1[3]);
      t2 = pk_bf16(s1[4], s1[5]);  t3 = pk_bf16(s1[6], s1[7]);
      pl32swap(t0, t2); pl32swap(t1, t3);
      wv[0] = t0; wv[1] = t1; wv[2] = t2; wv[3] = t3;
      const bf16x8 pf2 = __builtin_bit_cast(bf16x8, wv);
      t0 = pk_bf16(s1[8], s1[9]);   t1 = pk_bf16(s1[10], s1[11]);
      t2 = pk_bf16(s1[12], s1[13]); t3 = pk_bf16(s1[14], s1[15]);
      pl32swap(t0, t2); pl32swap(t1, t3);
      wv[0] = t0; wv[1] = t1; wv[2] = t2; wv[3] = t3;
      const bf16x8 pf3 = __builtin_bit_cast(bf16x8, wv);

      // ---- O^T += V^T * P ----
      const int vd0 = l31, vd1 = 32 + l31;
      const int vs0 = vswz(vd0) << 3, vs1 = vswz(vd1) << 3;
      bf16x8 vf;
      vf = *(const bf16x8*)&vc[vd0][(hi * 8) ^ vs0];
      o0 = __builtin_amdgcn_mfma_f32_32x32x16_bf16(vf, pf0, o0, 0, 0, 0);
      vf = *(const bf16x8*)&vc[vd0][(16 + hi * 8) ^ vs0];
      o0 = __builtin_amdgcn_mfma_f32_32x32x16_bf16(vf, pf1, o0, 0, 0, 0);
      vf = *(const bf16x8*)&vc[vd0][(32 + hi * 8) ^ vs0];
      o0 = __builtin_amdgcn_mfma_f32_32x32x16_bf16(vf, pf2, o0, 0, 0, 0);
      vf = *(const bf16x8*)&vc[vd0][(48 + hi * 8) ^ vs0];
      o0 = __builtin_amdgcn_mfma_f32_32x32x16_bf16(vf, pf3, o0, 0, 0, 0);
      vf = *(const bf16x8*)&vc[vd1][(hi * 8) ^ vs1];
      o1 = __builtin_amdgcn_mfma_f32_32x32x16_bf16(vf, pf0, o1, 0, 0, 0);
      vf = *(const bf16x8*)&vc[vd1][(16 + hi * 8) ^ vs1];
      o1 = __builtin_amdgcn_mfma_f32_32x32x16_bf16(vf, pf1, o1, 0, 0, 0);
      vf = *(const bf16x8*)&vc[vd1][(32 + hi * 8) ^ vs1];
      o1 = __builtin_amdgcn_mfma_f32_32x32x16_bf16(vf, pf2, o1, 0, 0, 0);
      vf = *(const bf16x8*)&vc[vd1][(48 + hi * 8) ^ vs1];
      o1 = __builtin_amdgcn_mfma_f32_32x32x16_bf16(vf, pf3, o1, 0, 0, 0);
    }

    // ---- STAGE_WRITE for t+1 (vmcnt wait lands here, after compute) ----
    if (pre) {
      const int nxt = cur ^ 1;
      uint4v w0;
      w0[0] = pk_bf16(a0[0], a0[1]); w0[1] = pk_bf16(a0[2], a0[3]);
      w0[2] = pk_bf16(a1[0], a1[1]); w0[3] = pk_bf16(a1[2], a1[3]);
      *(uint4v*)&k_lds[nxt][srow][scol ^ ssw] = w0;
      f32x4 bb[2] = { b0, b1 };
      #pragma unroll
      for (int c = 0; c < 2; ++c)
        #pragma unroll
        for (int e = 0; e < 4; ++e) {
          const int dd = scol + 4 * c + e;
          vt_lds[nxt][dd][srow ^ (vswz(dd) << 3)] = (__bf16)bb[c][e];
        }
    }
    __syncthreads();
  }

  // ---- epilogue: O^T regs -> rows of O ----
  const float inv = 1.0f / l;
  float* orow = Ob + (size_t)(wq + l31) * Dc;
  #pragma unroll
  for (int b = 0; b < 4; ++b) {
    f32x4 u0, u1;
    #pragma unroll
    for (int e = 0; e < 4; ++e) { u0[e] = o0[4 * b + e] * inv; u1[e] = o1[4 * b + e] * inv; }
    *(f32x4*)(orow + 8 * b + 4 * hi)      = u0;
    *(f32x4*)(orow + 32 + 8 * b + 4 * hi) = u1;
  }
}

}  // namespace

extern "C" void kernel_launch(void* const* d_in, const int* in_sizes, int n_in,
                              void* d_out, int out_size, void* d_ws, size_t ws_size,
                              hipStream_t stream) {
  const float* q = (const float*)d_in[0];
  const float* k = (const float*)d_in[1];
  const float* v = (const float*)d_in[2];
  // d_in[3] (triu mask) applied analytically.
  float* o = (float*)d_out;
  fattn_kernel<<<dim3(512), dim3(512), 0, stream>>>(q, k, v, o);
}

// Round 9
// 75.325 us; speedup vs baseline: 2.3688x; 1.1920x over previous
//
#include <hip/hip_runtime.h>
#include <hip/hip_bf16.h>

namespace {

constexpr int Bc = 4, Hc = 16, Sc = 2048, Dc = 64;

using bf16x2 = __attribute__((ext_vector_type(2))) __bf16;
using bf16x8 = __attribute__((ext_vector_type(8))) __bf16;
using f32x4  = __attribute__((ext_vector_type(4))) float;
using f32x16 = __attribute__((ext_vector_type(16))) float;
using uint4v = __attribute__((ext_vector_type(4))) unsigned int;

__device__ __forceinline__ float exp2_hw(float x) {
#if __has_builtin(__builtin_amdgcn_exp2f)
  return __builtin_amdgcn_exp2f(x);
#else
  return exp2f(x);
#endif
}

__device__ __forceinline__ unsigned pk_bf16(float a, float b) {
  bf16x2 t = { (__bf16)a, (__bf16)b };
  return __builtin_bit_cast(unsigned, t);
}

// v_permlane32_swap_b32 a,b with s_nop hazard padding (raw asm bypasses the
// post-RA hazard recognizer). Operands must be DISTINCT live values.
__device__ __forceinline__ void pl32swap(unsigned& a, unsigned& b) {
  asm volatile("s_nop 1\n\tv_permlane32_swap_b32 %0, %1\n\ts_nop 1"
               : "+v"(a), "+v"(b));
}
// Early-clobber dual-mov guarantees the two swap operands sit in distinct regs
// (round-3 lesson: copies of one SSA value may share a VGPR).
__device__ __forceinline__ void xhalf_pair(float x, float& lo, float& hi) {
  unsigned a, b;
  asm volatile("v_mov_b32 %0, %2\n\t"
               "v_mov_b32 %1, %2\n\t"
               "s_nop 1\n\t"
               "v_permlane32_swap_b32 %0, %1\n\t"
               "s_nop 1"
               : "=&v"(a), "=&v"(b)
               : "v"(x));
  lo = __builtin_bit_cast(float, a);
  hi = __builtin_bit_cast(float, b);
}
__device__ __forceinline__ float xhalf_max(float x) {
  float lo, hi; xhalf_pair(x, lo, hi); return fmaxf(lo, hi);
}
__device__ __forceinline__ float xhalf_sum(float x) {
  float lo, hi; xhalf_pair(x, lo, hi); return lo + hi;
}

__device__ __forceinline__ int vswz(int d) { return ((d >> 4) ^ d) & 7; }

// ROUND-9 = round-5 geometry (best known: 71 us, VGPR 104, no spills),
// softmax critical path shortened:
//  - log-depth max/sum trees (serial 31-op chains -> depth-5 trees)
//  - T13 defer-max: skip mnew/corr/o-rescale when __all(pmax <= m + 8)
// Rounds 6-8 lesson: leave the register allocator alone — launch_bounds
// stays (256,2); occupancy comes later, not via allocator caps.
__global__ __launch_bounds__(256, 2)
void fattn_kernel(const float* __restrict__ Q, const float* __restrict__ K,
                  const float* __restrict__ V, float* __restrict__ O) {
  const int tid  = threadIdx.x;
  const int wid  = tid >> 6;
  const int lane = tid & 63;
  const int l31  = lane & 31;
  const int hi   = lane >> 5;

  // XCD-bijective swizzle: XCD x owns bh in [8x, 8x+8); per-CU blocks equal (34 tiles).
  const int flat = blockIdx.x + 8 * blockIdx.y;
  const int w    = (flat & 7) * 64 + (flat >> 3);
  const int p    = w & 7;
  const int bh   = w >> 3;

  const size_t base = (size_t)bh * (Sc * Dc);
  const float* Qb = Q + base;
  const float* Kb = K + base;
  const float* Vb = V + base;
  float*       Ob = O + base;

  __shared__ __align__(16) __bf16 k_lds[2][64][64];   // K[k][d],  col ^= (k&7)<<3
  __shared__ __align__(16) __bf16 vt_lds[2][64][64];  // V^T[d][k], k ^= vswz(d)<<3

  const int srow = tid >> 2;         // staging row 0..63
  const int scol = (tid & 3) * 16;   // staging col chunk
  const int ssw  = (srow & 7) << 3;

  constexpr float QSC = 0.125f * 1.44269504088896f;  // 1/sqrt(D) * log2(e)

  for (int half = 0; half < 2; ++half) {
    const int qp = half ? (15 - p) : p;
    const int qb = qp * 128;
    const int wq = qb + wid * 32;
    const int nkb = 2 * qp + 2;

    // ---- Q fragment: lane holds Q[wq + l31][d = s*16 + hi*8 + j] ----
    bf16x8 qf[4];
    {
      const float* qrow = Qb + (size_t)(wq + l31) * Dc;
      #pragma unroll
      for (int s = 0; s < 4; ++s) {
        const float* src = qrow + s * 16 + hi * 8;
        f32x4 a0 = *(const f32x4*)src;
        f32x4 a1 = *(const f32x4*)(src + 4);
        uint4v wv;
        wv[0] = pk_bf16(a0[0] * QSC, a0[1] * QSC);
        wv[1] = pk_bf16(a0[2] * QSC, a0[3] * QSC);
        wv[2] = pk_bf16(a1[0] * QSC, a1[1] * QSC);
        wv[3] = pk_bf16(a1[2] * QSC, a1[3] * QSC);
        qf[s] = __builtin_bit_cast(bf16x8, wv);
      }
    }

    f32x16 o0, o1;   // O^T: col q = l31; row d = dh*32 + (i&3) + 8*(i>>2) + 4*hi
    #pragma unroll
    for (int i = 0; i < 16; ++i) { o0[i] = 0.f; o1[i] = 0.f; }
    float m = -1e30f, l = 0.f;

    // ---- prologue: stage tile 0 into buffer 0 ----
    {
      const float* ksrc = Kb + (size_t)srow * Dc + scol;
      f32x4 a0 = *(const f32x4*)ksrc;
      f32x4 a1 = *(const f32x4*)(ksrc + 4);
      f32x4 a2 = *(const f32x4*)(ksrc + 8);
      f32x4 a3 = *(const f32x4*)(ksrc + 12);
      const float* vsrc = Vb + (size_t)srow * Dc + scol;
      f32x4 b0 = *(const f32x4*)vsrc;
      f32x4 b1 = *(const f32x4*)(vsrc + 4);
      f32x4 b2 = *(const f32x4*)(vsrc + 8);
      f32x4 b3 = *(const f32x4*)(vsrc + 12);
      uint4v w0, w1;
      w0[0] = pk_bf16(a0[0], a0[1]); w0[1] = pk_bf16(a0[2], a0[3]);
      w0[2] = pk_bf16(a1[0], a1[1]); w0[3] = pk_bf16(a1[2], a1[3]);
      w1[0] = pk_bf16(a2[0], a2[1]); w1[1] = pk_bf16(a2[2], a2[3]);
      w1[2] = pk_bf16(a3[0], a3[1]); w1[3] = pk_bf16(a3[2], a3[3]);
      *(uint4v*)&k_lds[0][srow][scol ^ ssw]       = w0;
      *(uint4v*)&k_lds[0][srow][(scol + 8) ^ ssw] = w1;
      f32x4 bb[4] = { b0, b1, b2, b3 };
      #pragma unroll
      for (int c = 0; c < 4; ++c)
        #pragma unroll
        for (int e = 0; e < 4; ++e) {
          const int dd = scol + 4 * c + e;
          vt_lds[0][dd][srow ^ (vswz(dd) << 3)] = (__bf16)bb[c][e];
        }
    }
    __syncthreads();

    for (int t = 0; t < nkb; ++t) {
      const int cur   = t & 1;
      const int kbase = t * 64;
      const bool pre  = (t + 1 < nkb);

      // ---- issue next tile's global loads EARLY (in flight during compute) ----
      f32x4 a0, a1, a2, a3, b0, b1, b2, b3;
      if (pre) {
        const float* ksrc = Kb + (size_t)(kbase + 64 + srow) * Dc + scol;
        a0 = *(const f32x4*)ksrc;
        a1 = *(const f32x4*)(ksrc + 4);
        a2 = *(const f32x4*)(ksrc + 8);
        a3 = *(const f32x4*)(ksrc + 12);
        const float* vsrc = Vb + (size_t)(kbase + 64 + srow) * Dc + scol;
        b0 = *(const f32x4*)vsrc;
        b1 = *(const f32x4*)(vsrc + 4);
        b2 = *(const f32x4*)(vsrc + 8);
        b3 = *(const f32x4*)(vsrc + 12);
      }

      if (kbase <= wq + 31) {   // wave-active (no barriers inside)
        const __bf16 (*kc)[64] = k_lds[cur];
        const __bf16 (*vc)[64] = vt_lds[cur];

        // ---- S^T = K * Q^T ----
        f32x16 s0, s1;
        #pragma unroll
        for (int i = 0; i < 16; ++i) { s0[i] = 0.f; s1[i] = 0.f; }
        const int ksw = (l31 & 7) << 3;
        #pragma unroll
        for (int s = 0; s < 4; ++s) {
          bf16x8 kf = *(const bf16x8*)&kc[l31][(s * 16 + hi * 8) ^ ksw];
          s0 = __builtin_amdgcn_mfma_f32_32x32x16_bf16(kf, qf[s], s0, 0, 0, 0);
        }
        #pragma unroll
        for (int s = 0; s < 4; ++s) {
          bf16x8 kf = *(const bf16x8*)&kc[32 + l31][(s * 16 + hi * 8) ^ ksw];
          s1 = __builtin_amdgcn_mfma_f32_32x32x16_bf16(kf, qf[s], s1, 0, 0, 0);
        }

        // ---- causal mask (diagonal tiles only) ----
        if (kbase + 63 > wq) {
          const int q   = wq + l31;
          const int dq0 = q - (kbase + 4 * hi);
          const int dq1 = q - (kbase + 32 + 4 * hi);
          #pragma unroll
          for (int i = 0; i < 16; ++i) {
            const int off = (i & 3) + 8 * (i >> 2);
            if (off > dq0) s0[i] = -1e30f;
            if (off > dq1) s1[i] = -1e30f;
          }
        }

        // ---- tile max: log-depth tree (was a 31-deep serial fmax chain) ----
        float mx[16];
        #pragma unroll
        for (int i = 0; i < 16; ++i) mx[i] = fmaxf(s0[i], s1[i]);
        #pragma unroll
        for (int st = 8; st > 0; st >>= 1)
          #pragma unroll
          for (int i = 0; i < st; ++i) mx[i] = fmaxf(mx[i], mx[i + st]);
        const float pmax = xhalf_max(mx[0]);

        // ---- T13 defer-max: rescale only when max grew by > 8 (exp2 dom) ----
        float corr = 1.0f;
        if (!__all(pmax <= m + 8.0f)) {
          const float mnew = fmaxf(m, pmax);
          corr = exp2_hw(m - mnew);
          m = mnew;
          #pragma unroll
          for (int i = 0; i < 16; ++i) { o0[i] *= corr; o1[i] *= corr; }
        }

        #pragma unroll
        for (int i = 0; i < 16; ++i) {
          s0[i] = exp2_hw(s0[i] - m);
          s1[i] = exp2_hw(s1[i] - m);
        }

        // ---- tile sum: log-depth tree (was a 31-deep serial add chain) ----
        float sm[16];
        #pragma unroll
        for (int i = 0; i < 16; ++i) sm[i] = s0[i] + s1[i];
        #pragma unroll
        for (int st = 8; st > 0; st >>= 1)
          #pragma unroll
          for (int i = 0; i < st; ++i) sm[i] += sm[i + st];
        const float rs = xhalf_sum(sm[0]);
        l = l * corr + rs;

        // ---- P -> PV B-fragments: 16 cvt_pk + 8 permlane32_swap ----
        uint4v wv;
        unsigned t0, t1, t2, t3;
        t0 = pk_bf16(s0[0], s0[1]);  t1 = pk_bf16(s0[2], s0[3]);
        t2 = pk_bf16(s0[4], s0[5]);  t3 = pk_bf16(s0[6], s0[7]);
        pl32swap(t0, t2); pl32swap(t1, t3);
        wv[0] = t0; wv[1] = t1; wv[2] = t2; wv[3] = t3;
        const bf16x8 pf0 = __builtin_bit_cast(bf16x8, wv);
        t0 = pk_bf16(s0[8], s0[9]);   t1 = pk_bf16(s0[10], s0[11]);
        t2 = pk_bf16(s0[12], s0[13]); t3 = pk_bf16(s0[14], s0[15]);
        pl32swap(t0, t2); pl32swap(t1, t3);
        wv[0] = t0; wv[1] = t1; wv[2] = t2; wv[3] = t3;
        const bf16x8 pf1 = __builtin_bit_cast(bf16x8, wv);
        t0 = pk_bf16(s1[0], s1[1]);  t1 = pk_bf16(s1[2], s1[3]);
        t2 = pk_bf16(s1[4], s1[5]);  t3 = pk_bf16(s1[6], s1[7]);
        pl32swap(t0, t2); pl32swap(t1, t3);
        wv[0] = t0; wv[1] = t1; wv[2] = t2; wv[3] = t3;
        const bf16x8 pf2 = __builtin_bit_cast(bf16x8, wv);
        t0 = pk_bf16(s1[8], s1[9]);   t1 = pk_bf16(s1[10], s1[11]);
        t2 = pk_bf16(s1[12], s1[13]); t3 = pk_bf16(s1[14], s1[15]);
        pl32swap(t0, t2); pl32swap(t1, t3);
        wv[0] = t0; wv[1] = t1; wv[2] = t2; wv[3] = t3;
        const bf16x8 pf3 = __builtin_bit_cast(bf16x8, wv);

        // ---- O^T += V^T * P ----
        const int vd0 = l31, vd1 = 32 + l31;
        const int vs0 = vswz(vd0) << 3, vs1 = vswz(vd1) << 3;
        bf16x8 vf;
        vf = *(const bf16x8*)&vc[vd0][(hi * 8) ^ vs0];
        o0 = __builtin_amdgcn_mfma_f32_32x32x16_bf16(vf, pf0, o0, 0, 0, 0);
        vf = *(const bf16x8*)&vc[vd0][(16 + hi * 8) ^ vs0];
        o0 = __builtin_amdgcn_mfma_f32_32x32x16_bf16(vf, pf1, o0, 0, 0, 0);
        vf = *(const bf16x8*)&vc[vd0][(32 + hi * 8) ^ vs0];
        o0 = __builtin_amdgcn_mfma_f32_32x32x16_bf16(vf, pf2, o0, 0, 0, 0);
        vf = *(const bf16x8*)&vc[vd0][(48 + hi * 8) ^ vs0];
        o0 = __builtin_amdgcn_mfma_f32_32x32x16_bf16(vf, pf3, o0, 0, 0, 0);
        vf = *(const bf16x8*)&vc[vd1][(hi * 8) ^ vs1];
        o1 = __builtin_amdgcn_mfma_f32_32x32x16_bf16(vf, pf0, o1, 0, 0, 0);
        vf = *(const bf16x8*)&vc[vd1][(16 + hi * 8) ^ vs1];
        o1 = __builtin_amdgcn_mfma_f32_32x32x16_bf16(vf, pf1, o1, 0, 0, 0);
        vf = *(const bf16x8*)&vc[vd1][(32 + hi * 8) ^ vs1];
        o1 = __builtin_amdgcn_mfma_f32_32x32x16_bf16(vf, pf2, o1, 0, 0, 0);
        vf = *(const bf16x8*)&vc[vd1][(48 + hi * 8) ^ vs1];
        o1 = __builtin_amdgcn_mfma_f32_32x32x16_bf16(vf, pf3, o1, 0, 0, 0);
      }

      // ---- STAGE_WRITE for t+1 (vmcnt wait lands here, after compute) ----
      if (pre) {
        const int nxt = cur ^ 1;
        uint4v w0, w1;
        w0[0] = pk_bf16(a0[0], a0[1]); w0[1] = pk_bf16(a0[2], a0[3]);
        w0[2] = pk_bf16(a1[0], a1[1]); w0[3] = pk_bf16(a1[2], a1[3]);
        w1[0] = pk_bf16(a2[0], a2[1]); w1[1] = pk_bf16(a2[2], a2[3]);
        w1[2] = pk_bf16(a3[0], a3[1]); w1[3] = pk_bf16(a3[2], a3[3]);
        *(uint4v*)&k_lds[nxt][srow][scol ^ ssw]       = w0;
        *(uint4v*)&k_lds[nxt][srow][(scol + 8) ^ ssw] = w1;
        f32x4 bb[4] = { b0, b1, b2, b3 };
        #pragma unroll
        for (int c = 0; c < 4; ++c)
          #pragma unroll
          for (int e = 0; e < 4; ++e) {
            const int dd = scol + 4 * c + e;
            vt_lds[nxt][dd][srow ^ (vswz(dd) << 3)] = (__bf16)bb[c][e];
          }
      }
      __syncthreads();
    }

    // ---- epilogue: O^T regs -> rows of O ----
    const float inv = 1.0f / l;
    float* orow = Ob + (size_t)(wq + l31) * Dc;
    #pragma unroll
    for (int b = 0; b < 4; ++b) {
      f32x4 u0, u1;
      #pragma unroll
      for (int e = 0; e < 4; ++e) { u0[e] = o0[4 * b + e] * inv; u1[e] = o1[4 * b + e] * inv; }
      *(f32x4*)(orow + 8 * b + 4 * hi)      = u0;
      *(f32x4*)(orow + 32 + 8 * b + 4 * hi) = u1;
    }
    __syncthreads();  // LDS reuse guard before next panel's prologue
  }
}

}  // namespace

extern "C" void kernel_launch(void* const* d_in, const int* in_sizes, int n_in,
                              void* d_out, int out_size, void* d_ws, size_t ws_size,
                              hipStream_t stream) {
  const float* q = (const float*)d_in[0];
  const float* k = (const float*)d_in[1];
  const float* v = (const float*)d_in[2];
  // d_in[3] (triu mask) applied analytically.
  float* o = (float*)d_out;
  dim3 grid(8, Bc * Hc);
  fattn_kernel<<<grid, dim3(256), 0, stream>>>(q, k, v, o);
}